// Round 1
// baseline (1069.585 us; speedup 1.0000x reference)
//
#include <hip/hip_runtime.h>
#include <math.h>

#define NEG -1e30f

constexpr int B  = 16;
constexpr int T  = 200;
constexpr int U  = 100;
constexpr int U1 = 101;   // U+1
constexpr int V  = 512;
constexpr int NDIAG = T + U1 - 1;  // 300 anti-diagonals

__device__ __forceinline__ float logaddexpf_(float a, float b) {
    float mx = fmaxf(a, b);
    float mn = fminf(a, b);
    return mx + log1pf(__expf(mn - mx));
}

// Kernel 1: one 64-lane wave per (b,t,u) row of 512 logits.
// Computes logsumexp and writes blank_lp / emit_lp in DIAGONAL-major layout:
//   idx = b*NDIAG*U1 + (t+u)*U1 + u
// so the DP kernel's per-diagonal reads are contiguous.
__global__ void lse_extract_kernel(const float* __restrict__ acts,
                                   const int*   __restrict__ labels,
                                   const int*   __restrict__ label_lens,
                                   float* __restrict__ blankD,
                                   float* __restrict__ emitD) {
    const int nrows = B * T * U1;
    int gid   = blockIdx.x * blockDim.x + threadIdx.x;
    int wave  = gid >> 6;
    int lane  = threadIdx.x & 63;
    int nwaves = (gridDim.x * blockDim.x) >> 6;
    for (int row = wave; row < nrows; row += nwaves) {
        const float*  p  = acts + (size_t)row * V;
        const float4* p4 = (const float4*)p;
        float4 x0 = p4[lane * 2];
        float4 x1 = p4[lane * 2 + 1];
        float m = fmaxf(fmaxf(fmaxf(x0.x, x0.y), fmaxf(x0.z, x0.w)),
                        fmaxf(fmaxf(x1.x, x1.y), fmaxf(x1.z, x1.w)));
        #pragma unroll
        for (int off = 32; off; off >>= 1) m = fmaxf(m, __shfl_xor(m, off, 64));
        float s = __expf(x0.x - m) + __expf(x0.y - m) + __expf(x0.z - m) + __expf(x0.w - m)
                + __expf(x1.x - m) + __expf(x1.y - m) + __expf(x1.z - m) + __expf(x1.w - m);
        #pragma unroll
        for (int off = 32; off; off >>= 1) s += __shfl_xor(s, off, 64);
        float lse = m + __logf(s);
        if (lane == 0) {
            int u  = row % U1;
            int bt = row / U1;
            int t  = bt % T;
            int b  = bt / T;
            size_t dpos = ((size_t)b * NDIAG + (t + u)) * U1 + u;
            blankD[dpos] = x0.x - lse;          // x0.x == p[0] on lane 0 (blank logit)
            float e = NEG;
            if (u < label_lens[b]) {            // u == U is always masked (label_lens <= U)
                int lab = labels[b * U + u];
                e = p[lab] - lse;               // L1/L2 hit — row was just streamed
            }
            emitD[dpos] = e;
        }
    }
}

// Kernel 2: diagonal-wavefront forward DP. One block per batch element,
// one thread per u. Double-buffered diagonal in LDS; inputs for the next
// diagonal are prefetched into registers before the barrier.
__global__ void __launch_bounds__(128) dp_kernel(const float* __restrict__ blankD,
                                                 const float* __restrict__ emitD,
                                                 const int*   __restrict__ act_lens,
                                                 const int*   __restrict__ label_lens,
                                                 float* __restrict__ costs) {
    int b = blockIdx.x;
    int u = threadIdx.x;
    const float* bl = blankD + (size_t)b * NDIAG * U1;
    const float* em = emitD  + (size_t)b * NDIAG * U1;
    int t_end = act_lens[b] - 1;
    int u_end = label_lens[b];
    __shared__ float diag[2][U1];
    if (u == 0) diag[0][0] = 0.0f;              // alpha[0][0] = 0
    // preload diagonal-0 inputs (used when computing diagonal 1)
    float bl_r = 0.0f, em_r = 0.0f;
    if (u < U1) {
        bl_r = bl[u];                            // blank at (t-1, u)   ~ prev diag, pos u
        if (u >= 1) em_r = em[u - 1];            // emit  at (t,  u-1)  ~ prev diag, pos u-1
    }
    __syncthreads();
    for (int d = 1; d < NDIAG; ++d) {
        const float* prev = diag[(d - 1) & 1];
        float*       cur  = diag[d & 1];
        int  t = d - u;
        bool active = (u < U1) && (t >= 0) && (t < T);
        float val = 0.0f;
        if (active) {
            if (t == 0)            val = prev[u - 1] + em_r;                 // emit-only row
            else if (u == 0)       val = prev[0] + bl_r;                     // blank-only col
            else                   val = logaddexpf_(prev[u] + bl_r,
                                                     prev[u - 1] + em_r);
        }
        // prefetch next diagonal's inputs (contiguous, L2-hot) before the barrier
        float bl_n = 0.0f, em_n = 0.0f;
        if (u < U1 && d < NDIAG - 1) {
            bl_n = bl[d * U1 + u];
            if (u >= 1) em_n = em[d * U1 + u - 1];
        }
        if (active) {
            cur[u] = val;
            if (t == t_end && u == u_end)
                costs[b] = -(val + bl[d * U1 + u]);   // -ll = -(alpha + blank_lp)
        }
        bl_r = bl_n;
        em_r = em_n;
        __syncthreads();
    }
}

// Kernel 3: mean of the 16 per-utterance costs.
__global__ void finalize_kernel(const float* __restrict__ costs, float* __restrict__ out) {
    int lane = threadIdx.x;
    float v = (lane < B) ? costs[lane] : 0.0f;
    #pragma unroll
    for (int off = 8; off; off >>= 1) v += __shfl_xor(v, off, 64);
    if (lane == 0) out[0] = v * (1.0f / (float)B);
}

extern "C" void kernel_launch(void* const* d_in, const int* in_sizes, int n_in,
                              void* d_out, int out_size, void* d_ws, size_t ws_size,
                              hipStream_t stream) {
    const float* acts       = (const float*)d_in[0];
    const int*   labels     = (const int*)d_in[1];
    const int*   act_lens   = (const int*)d_in[2];
    const int*   label_lens = (const int*)d_in[3];
    float* out = (float*)d_out;

    // Workspace layout (floats): blankD | emitD | costs  (~3.7 MB total)
    float* blankD = (float*)d_ws;
    float* emitD  = blankD + (size_t)B * NDIAG * U1;
    float* costs  = emitD  + (size_t)B * NDIAG * U1;

    lse_extract_kernel<<<4096, 256, 0, stream>>>(acts, labels, label_lens, blankD, emitD);
    dp_kernel<<<B, 128, 0, stream>>>(blankD, emitD, act_lens, label_lens, costs);
    finalize_kernel<<<1, 64, 0, stream>>>(costs, out);
}